// Round 11
// baseline (15016.800 us; speedup 1.0000x reference)
//
#include <hip/hip_runtime.h>
#include <stdint.h>

// Problem dims (fixed by the reference)
#define BSZ   1024
#define TT    8
#define DD    512
#define HH    512
#define NSEQ  (BSZ*TT)          // 8192 sequential steps per direction
#define FOURH (4*HH)            // 2048
#define POISON 0xAAAAAAAAu
#define G_ELEMS  ((size_t)2*NSEQ*FOURH)      // 33,554,432 floats (128 MB)
#define HB_ELEMS ((size_t)2*(NSEQ+1)*HH)     //  8,389,632 floats (32 MB)
#define POLL_CAP (1<<16)

typedef __attribute__((ext_vector_type(4))) float vf4;

// Device-scope 32B load (bypasses L1+L2; serial wait — r7/r10 proven form).
__device__ __forceinline__ void ld2x16_dev(const float* p, vf4& a, vf4& b){
  asm volatile("global_load_dwordx4 %0, %2, off sc1\n\t"
               "global_load_dwordx4 %1, %2, off offset:16 sc1\n\t"
               "s_waitcnt vmcnt(0)"
               : "=v"(a), "=v"(b) : "v"(p) : "memory");
}
// Device-scope 4B publish store.
__device__ __forceinline__ void st_dev(float* p, float v){
  asm volatile("global_store_dword %0, %1, off sc1"
               :: "v"(p), "v"(v) : "memory");
}

// ---------------------------------------------------------------------------
// Init: poison the h-pipeline buffer, seed slot 0 with h0 (LSB-flip if it
// happens to equal the poison bit pattern).
// ---------------------------------------------------------------------------
__global__ void init_hbuf_k(float* __restrict__ hbuf, const float* __restrict__ h0)
{
  size_t idx = (size_t)blockIdx.x*blockDim.x + threadIdx.x;
  if (idx >= HB_ELEMS) return;
  int j = (int)(idx % HH);
  size_t r = idx / HH;
  int t   = (int)(r % (NSEQ+1));
  int dir = (int)(r / (NSEQ+1));
  uint32_t v;
  if (t == 0){
    uint32_t u = __float_as_uint(h0[dir*HH + j]);
    if (u == POISON) u ^= 1u;
    v = u;
  } else {
    v = POISON;
  }
  ((uint32_t*)hbuf)[idx] = v;
}

// ---------------------------------------------------------------------------
// Input-side GEMM: g[dir][n][m] = x[row]·W_ih_dir[m] + b_dir[m]
//   dir 0: row = n ; dir 1: row = n^7  (per-sample time reversal, T=8)
// ---------------------------------------------------------------------------
__global__ __launch_bounds__(256) void gemm_ih_k(
    const float* __restrict__ x,
    const float* __restrict__ Wf, const float* __restrict__ bf,
    const float* __restrict__ Wb, const float* __restrict__ bb,
    float* __restrict__ g)
{
  const int bm = blockIdx.x;          // 128 row tiles
  const int bn = blockIdx.y;          // 64 col tiles over combined N=4096
  const int n0  = bm*64;
  const int m0g = bn*64;
  const int dir = m0g >> 11;          // /2048
  const int m0  = m0g & 2047;
  const float* __restrict__ W    = dir ? Wb : Wf;
  const float* __restrict__ bias = dir ? bb : bf;

  __shared__ float As[32][68];
  __shared__ float Bs[32][68];

  const int tid = threadIdx.x;
  const int tx = tid & 15, ty = tid >> 4;
  float acc[4][4] = {};

  const int lr = tid >> 2;            // 0..63
  const int lk = (tid & 3) * 8;       // 0,8,16,24
  int arow = n0 + lr; if (dir) arow ^= 7;
  const float* ap = &x[(size_t)arow*DD];
  const float* wp = &W[(size_t)(m0+lr)*DD];

  for (int k0 = 0; k0 < DD; k0 += 32){
    float4 a0 = *(const float4*)&ap[k0+lk];
    float4 a1 = *(const float4*)&ap[k0+lk+4];
    float4 w0 = *(const float4*)&wp[k0+lk];
    float4 w1 = *(const float4*)&wp[k0+lk+4];
    __syncthreads();
    As[lk+0][lr]=a0.x; As[lk+1][lr]=a0.y; As[lk+2][lr]=a0.z; As[lk+3][lr]=a0.w;
    As[lk+4][lr]=a1.x; As[lk+5][lr]=a1.y; As[lk+6][lr]=a1.z; As[lk+7][lr]=a1.w;
    Bs[lk+0][lr]=w0.x; Bs[lk+1][lr]=w0.y; Bs[lk+2][lr]=w0.z; Bs[lk+3][lr]=w0.w;
    Bs[lk+4][lr]=w1.x; Bs[lk+5][lr]=w1.y; Bs[lk+6][lr]=w1.z; Bs[lk+7][lr]=w1.w;
    __syncthreads();
    #pragma unroll
    for (int kk = 0; kk < 32; kk++){
      float4 av = *(const float4*)&As[kk][ty*4];
      float4 bv = *(const float4*)&Bs[kk][tx*4];
      acc[0][0]+=av.x*bv.x; acc[0][1]+=av.x*bv.y; acc[0][2]+=av.x*bv.z; acc[0][3]+=av.x*bv.w;
      acc[1][0]+=av.y*bv.x; acc[1][1]+=av.y*bv.y; acc[1][2]+=av.y*bv.z; acc[1][3]+=av.y*bv.w;
      acc[2][0]+=av.z*bv.x; acc[2][1]+=av.z*bv.y; acc[2][2]+=av.z*bv.z; acc[2][3]+=av.z*bv.w;
      acc[3][0]+=av.w*bv.x; acc[3][1]+=av.w*bv.y; acc[3][2]+=av.w*bv.z; acc[3][3]+=av.w*bv.w;
    }
  }

  const size_t gbase = (size_t)dir*NSEQ*FOURH;
  #pragma unroll
  for (int i = 0; i < 4; i++){
    const int n = n0 + ty*4 + i;
    #pragma unroll
    for (int j = 0; j < 4; j++){
      const int m = m0 + tx*4 + j;
      g[gbase + (size_t)n*FOURH + m] = acc[i][j] + bias[m];
    }
  }
}

// ---------------------------------------------------------------------------
// Sequential bidirectional scan — r10 fabric (serial sleep(1) poll, strided
// LDS partition, rcp gates, publish-first, __syncthreads barriers) with ONE
// change: gate math + publish move from wave 0 (tid<16) to WAVE 1 lanes
// 64-79 (merged with the g-loader role — the exact r8 arrangement, which
// passed correctness). Wave 0's vmcnt stream now contains ONLY poll loads:
// its first sample of step t+1 no longer serializes behind the publish/out
// store acks (~600-900cy) and instead overlaps the publish latency. This is
// the r8 experiment re-run WITHOUT the confound (r8's unthrottled dual-slot
// sampler, which FETCH=444MB showed was the actual regression cause).
// LDS anti-overwrite ordering = r8-validated transitive argument: hsh4/zbuf/
// gsh rewrites for t+1 happen after wave 0's poll-hit of t+1, which requires
// wave 1's publish of t, which is after wave 1's zbuf/gsh reads of t.
// ---------------------------------------------------------------------------
#define DPP_ROR_ADD(v, ctrl) do { \
    int _t = __builtin_amdgcn_update_dpp(0, __float_as_int(v), (ctrl), 0xf, 0xf, false); \
    (v) += __int_as_float(_t); } while (0)

__global__ __launch_bounds__(1024, 4) void scan_k(
    const float* __restrict__ Whh_f, const float* __restrict__ Whh_b,
    const float* __restrict__ c0, const float* __restrict__ g,
    float* __restrict__ hbuf, float* __restrict__ out)
{
  const int bx  = blockIdx.x;
  const int dir = bx >> 5;
  const int w   = bx & 31;
  const int j0  = w << 4;
  const int tid  = threadIdx.x;
  const int lane = tid & 63;
  const int wv   = tid >> 6;
  const int s    = lane & 31;         // k-slice id (32 slices x 16 strided cols)
  const int rb   = lane >> 5;
  const int r0   = (wv << 2) + rb;    // z-rows: wave wv covers rows 4wv..4wv+3
  const int r1   = r0 + 2;

  const float* __restrict__ Whh = dir ? Whh_b : Whh_f;

  __shared__ vf4  hsh4[128];          // h[t] broadcast, LINEAR chunks
  __shared__ float zbuf[64];
  __shared__ float gsh[64];
  __shared__ int dead;

  // Recurrent weights for rows r0/r1 over this lane's strided column set:
  // wX[4q+j] = W[row][128q + 4s + j]  (matches h4{a,b,c,d}[j] below).
  float wA[16], wB[16];
  {
    const int gA = r0 >> 4, hA = r0 & 15;
    const int gB = r1 >> 4, hB = r1 & 15;
    const float* pa = &Whh[(size_t)(gA*HH + j0 + hA)*HH];
    const float* pb = &Whh[(size_t)(gB*HH + j0 + hB)*HH];
    #pragma unroll
    for (int q = 0; q < 4; q++){
      float4 va = *(const float4*)&pa[q*128 + (s<<2)];
      wA[4*q+0]=va.x; wA[4*q+1]=va.y; wA[4*q+2]=va.z; wA[4*q+3]=va.w;
      float4 vb = *(const float4*)&pb[q*128 + (s<<2)];
      wB[4*q+0]=vb.x; wB[4*q+1]=vb.y; wB[4*q+2]=vb.z; wB[4*q+3]=vb.w;
    }
  }

  // Wave-1 core lanes (tid 64..79): g loader + gate math + publish.
  const bool w1core = (tid >= 64) && (tid < 80);
  const int  gl = tid - 64;

  float cst = 0.f;
  if (w1core) cst = c0[dir*HH + j0 + gl];
  if (tid == 0) dead = 0;
  __syncthreads();

  float* __restrict__ hb = hbuf + (size_t)dir*(NSEQ+1)*HH;
  const float* __restrict__ gbp = g + (size_t)dir*NSEQ*FOURH;

  for (int t = 0; t < NSEQ; t++){
    // g prefetch on wave 1 (off the polling wave's critical path).
    float pgi=0.f, pgf=0.f, pgg=0.f, pgo=0.f;
    if (w1core){
      const float* gp = &gbp[(size_t)t*FOURH + j0 + gl];
      pgi = gp[0]; pgf = gp[HH]; pgg = gp[2*HH]; pgo = gp[3*HH];
    }

    // Wave 0: poll h[t] (8 floats/lane) until no poison remains.
    // Store-free vmcnt stream: first sample issues immediately after
    // barrier #2 of t-1 and overlaps wave 1's publish latency.
    if (wv == 0){
      const float* hp = &hb[(size_t)t*HH + (lane<<3)];
      vf4 a, b;
      int it = 0;
      for (;;){
        ld2x16_dev(hp, a, b);
        bool ok = (__float_as_uint(a.x)!=POISON) & (__float_as_uint(a.y)!=POISON)
                & (__float_as_uint(a.z)!=POISON) & (__float_as_uint(a.w)!=POISON)
                & (__float_as_uint(b.x)!=POISON) & (__float_as_uint(b.y)!=POISON)
                & (__float_as_uint(b.z)!=POISON) & (__float_as_uint(b.w)!=POISON);
        if (ok) break;
        if (++it > POLL_CAP){ dead = 1; break; }
        __builtin_amdgcn_s_sleep(1);
      }
      // Linear LDS broadcast: lane L -> chunks {2L, 2L+1}.
      const int c0i = lane << 1;
      hsh4[c0i]     = a;
      hsh4[c0i + 1] = b;
    }
    __syncthreads();
    if (dead) break;

    // ---- read this lane's strided h slice: chunks {s, 32+s, 64+s, 96+s} ----
    vf4 h4a = hsh4[s];
    vf4 h4b = hsh4[32 + s];
    vf4 h4c = hsh4[64 + s];
    vf4 h4d = hsh4[96 + s];

    // Two 16-long dot products per lane (4 independent FMA chains).
    float a0=0.f, a1=0.f, b0=0.f, b1=0.f;
    a0 += wA[ 0]*h4a.x; a1 += wA[ 1]*h4a.y; a0 += wA[ 2]*h4a.z; a1 += wA[ 3]*h4a.w;
    a0 += wA[ 4]*h4b.x; a1 += wA[ 5]*h4b.y; a0 += wA[ 6]*h4b.z; a1 += wA[ 7]*h4b.w;
    a0 += wA[ 8]*h4c.x; a1 += wA[ 9]*h4c.y; a0 += wA[10]*h4c.z; a1 += wA[11]*h4c.w;
    a0 += wA[12]*h4d.x; a1 += wA[13]*h4d.y; a0 += wA[14]*h4d.z; a1 += wA[15]*h4d.w;
    b0 += wB[ 0]*h4a.x; b1 += wB[ 1]*h4a.y; b0 += wB[ 2]*h4a.z; b1 += wB[ 3]*h4a.w;
    b0 += wB[ 4]*h4b.x; b1 += wB[ 5]*h4b.y; b0 += wB[ 6]*h4b.z; b1 += wB[ 7]*h4b.w;
    b0 += wB[ 8]*h4c.x; b1 += wB[ 9]*h4c.y; b0 += wB[10]*h4c.z; b1 += wB[11]*h4c.w;
    b0 += wB[12]*h4d.x; b1 += wB[13]*h4d.y; b0 += wB[14]*h4d.z; b1 += wB[15]*h4d.w;
    float accA = a0 + a1, accB = b0 + b1;

    // Reduce across 32 k-slices: 4 DPP row-rotates (within 16) + xor-16 swizzle.
    DPP_ROR_ADD(accA, 0x128); DPP_ROR_ADD(accA, 0x124);
    DPP_ROR_ADD(accA, 0x122); DPP_ROR_ADD(accA, 0x121);
    accA += __int_as_float(__builtin_amdgcn_ds_swizzle(__float_as_int(accA), 0x401F));
    DPP_ROR_ADD(accB, 0x128); DPP_ROR_ADD(accB, 0x124);
    DPP_ROR_ADD(accB, 0x122); DPP_ROR_ADD(accB, 0x121);
    accB += __int_as_float(__builtin_amdgcn_ds_swizzle(__float_as_int(accB), 0x401F));

    if (s == 0){ zbuf[r0] = accA; zbuf[r1] = accB; }
    if (w1core){ gsh[gl]=pgi; gsh[16+gl]=pgf; gsh[32+gl]=pgg; gsh[48+gl]=pgo; }
    __syncthreads();

    // ---- gate math + state update + publish — WAVE 1 lanes 64..79 ----
    if (w1core){
      float zi = zbuf[gl]      + gsh[gl];
      float zf = zbuf[16 + gl] + gsh[16 + gl];
      float zg = zbuf[32 + gl] + gsh[32 + gl];
      float zo = zbuf[48 + gl] + gsh[48 + gl];
      float si = __builtin_amdgcn_rcpf(1.f + __expf(-zi));
      float sf = __builtin_amdgcn_rcpf(1.f + __expf(-zf));
      float so = __builtin_amdgcn_rcpf(1.f + __expf(-zo));
      float tg = 1.f - 2.f*__builtin_amdgcn_rcpf(__expf(2.f*zg) + 1.f);
      cst = sf*cst + si*tg;
      float tc = 1.f - 2.f*__builtin_amdgcn_rcpf(__expf(2.f*cst) + 1.f);
      float hv  = so*tc;
      uint32_t u = __float_as_uint(hv);
      if (u == POISON) hv = __uint_as_float(u ^ 1u);   // keep poison unambiguous

      st_dev(&hb[(size_t)(t+1)*HH + j0 + gl], hv);     // publish FIRST (coalesced)

      const int n = dir ? (t ^ 7) : t;                 // undo per-sample reversal
      out[(size_t)n*(2*HH) + dir*HH + j0 + gl] = hv;

      if (t == NSEQ-1){
        out[(size_t)NSEQ*2*HH + dir*HH + j0 + gl] = hv;          // h_n
        out[(size_t)NSEQ*2*HH + 2*HH + dir*HH + j0 + gl] = cst;  // c_n
      }
    }
    // No trailing barrier: next-step hsh4/zbuf/gsh writes are gated behind
    // barrier #1 of t+1 (requires wave 0's poll-hit of t+1, which requires
    // wave 1's publish of t, which follows wave 1's zbuf/gsh reads of t).
  }
}

// ---------------------------------------------------------------------------
extern "C" void kernel_launch(void* const* d_in, const int* in_sizes, int n_in,
                              void* d_out, int out_size, void* d_ws, size_t ws_size,
                              hipStream_t stream)
{
  const float* x    = (const float*)d_in[0];
  const float* h0   = (const float*)d_in[1];
  const float* c0   = (const float*)d_in[2];
  const float* Wihf = (const float*)d_in[3];
  const float* Whhf = (const float*)d_in[4];
  const float* bf   = (const float*)d_in[5];
  const float* Wihb = (const float*)d_in[6];
  const float* Whhb = (const float*)d_in[7];
  const float* bb   = (const float*)d_in[8];
  float* out = (float*)d_out;
  float* ws  = (float*)d_ws;

  float* g    = ws;                 // [2][8192][2048] fp32
  float* hbuf = ws + G_ELEMS;       // [2][8193][512]  fp32

  {
    int total = (int)HB_ELEMS;
    int blocks = (total + 255) / 256;
    init_hbuf_k<<<blocks, 256, 0, stream>>>(hbuf, h0);
  }
  {
    dim3 grid(NSEQ/64, (2*FOURH)/64);   // (128, 64)
    gemm_ih_k<<<grid, 256, 0, stream>>>(x, Wihf, bf, Wihb, bb, g);
  }
  scan_k<<<64, 1024, 0, stream>>>(Whhf, Whhb, c0, g, hbuf, out);
}

// Round 12
// 11484.807 us; speedup vs baseline: 1.3075x; 1.3075x over previous
//
#include <hip/hip_runtime.h>
#include <stdint.h>

// Problem dims (fixed by the reference)
#define BSZ   1024
#define TT    8
#define DD    512
#define HH    512
#define NSEQ  (BSZ*TT)          // 8192 sequential steps per direction
#define FOURH (4*HH)            // 2048
#define POISON 0xAAAAAAAAu
#define G_ELEMS  ((size_t)2*NSEQ*FOURH)      // 33,554,432 floats (128 MB)
#define HB_ELEMS ((size_t)2*(NSEQ+1)*HH)     //  8,389,632 floats (32 MB)
#define POLL_CAP (1<<16)

typedef __attribute__((ext_vector_type(4))) float vf4;

// Device-scope 32B load (bypasses L1+L2; serial wait — r7/r10 proven form).
__device__ __forceinline__ void ld2x16_dev(const float* p, vf4& a, vf4& b){
  asm volatile("global_load_dwordx4 %0, %2, off sc1\n\t"
               "global_load_dwordx4 %1, %2, off offset:16 sc1\n\t"
               "s_waitcnt vmcnt(0)"
               : "=v"(a), "=v"(b) : "v"(p) : "memory");
}
// ATOMIC publish: global_atomic_swap (no-return form) commits at the
// coherence point immediately — cannot dwell in write-combine/store queues
// the way a plain global_store_dword may. Device scope (sc1).
__device__ __forceinline__ void st_pub(float* p, float v){
  asm volatile("global_atomic_swap %0, %1, off sc1"
               :: "v"(p), "v"(v) : "memory");
}

// ---------------------------------------------------------------------------
// Init: poison the h-pipeline buffer, seed slot 0 with h0 (LSB-flip if it
// happens to equal the poison bit pattern).
// ---------------------------------------------------------------------------
__global__ void init_hbuf_k(float* __restrict__ hbuf, const float* __restrict__ h0)
{
  size_t idx = (size_t)blockIdx.x*blockDim.x + threadIdx.x;
  if (idx >= HB_ELEMS) return;
  int j = (int)(idx % HH);
  size_t r = idx / HH;
  int t   = (int)(r % (NSEQ+1));
  int dir = (int)(r / (NSEQ+1));
  uint32_t v;
  if (t == 0){
    uint32_t u = __float_as_uint(h0[dir*HH + j]);
    if (u == POISON) u ^= 1u;
    v = u;
  } else {
    v = POISON;
  }
  ((uint32_t*)hbuf)[idx] = v;
}

// ---------------------------------------------------------------------------
// Input-side GEMM: g[dir][n][m] = x[row]·W_ih_dir[m] + b_dir[m]
//   dir 0: row = n ; dir 1: row = n^7  (per-sample time reversal, T=8)
// ---------------------------------------------------------------------------
__global__ __launch_bounds__(256) void gemm_ih_k(
    const float* __restrict__ x,
    const float* __restrict__ Wf, const float* __restrict__ bf,
    const float* __restrict__ Wb, const float* __restrict__ bb,
    float* __restrict__ g)
{
  const int bm = blockIdx.x;          // 128 row tiles
  const int bn = blockIdx.y;          // 64 col tiles over combined N=4096
  const int n0  = bm*64;
  const int m0g = bn*64;
  const int dir = m0g >> 11;          // /2048
  const int m0  = m0g & 2047;
  const float* __restrict__ W    = dir ? Wb : Wf;
  const float* __restrict__ bias = dir ? bb : bf;

  __shared__ float As[32][68];
  __shared__ float Bs[32][68];

  const int tid = threadIdx.x;
  const int tx = tid & 15, ty = tid >> 4;
  float acc[4][4] = {};

  const int lr = tid >> 2;            // 0..63
  const int lk = (tid & 3) * 8;       // 0,8,16,24
  int arow = n0 + lr; if (dir) arow ^= 7;
  const float* ap = &x[(size_t)arow*DD];
  const float* wp = &W[(size_t)(m0+lr)*DD];

  for (int k0 = 0; k0 < DD; k0 += 32){
    float4 a0 = *(const float4*)&ap[k0+lk];
    float4 a1 = *(const float4*)&ap[k0+lk+4];
    float4 w0 = *(const float4*)&wp[k0+lk];
    float4 w1 = *(const float4*)&wp[k0+lk+4];
    __syncthreads();
    As[lk+0][lr]=a0.x; As[lk+1][lr]=a0.y; As[lk+2][lr]=a0.z; As[lk+3][lr]=a0.w;
    As[lk+4][lr]=a1.x; As[lk+5][lr]=a1.y; As[lk+6][lr]=a1.z; As[lk+7][lr]=a1.w;
    Bs[lk+0][lr]=w0.x; Bs[lk+1][lr]=w0.y; Bs[lk+2][lr]=w0.z; Bs[lk+3][lr]=w0.w;
    Bs[lk+4][lr]=w1.x; Bs[lk+5][lr]=w1.y; Bs[lk+6][lr]=w1.z; Bs[lk+7][lr]=w1.w;
    __syncthreads();
    #pragma unroll
    for (int kk = 0; kk < 32; kk++){
      float4 av = *(const float4*)&As[kk][ty*4];
      float4 bv = *(const float4*)&Bs[kk][tx*4];
      acc[0][0]+=av.x*bv.x; acc[0][1]+=av.x*bv.y; acc[0][2]+=av.x*bv.z; acc[0][3]+=av.x*bv.w;
      acc[1][0]+=av.y*bv.x; acc[1][1]+=av.y*bv.y; acc[1][2]+=av.y*bv.z; acc[1][3]+=av.y*bv.w;
      acc[2][0]+=av.z*bv.x; acc[2][1]+=av.z*bv.y; acc[2][2]+=av.z*bv.z; acc[2][3]+=av.z*bv.w;
      acc[3][0]+=av.w*bv.x; acc[3][1]+=av.w*bv.y; acc[3][2]+=av.w*bv.z; acc[3][3]+=av.w*bv.w;
    }
  }

  const size_t gbase = (size_t)dir*NSEQ*FOURH;
  #pragma unroll
  for (int i = 0; i < 4; i++){
    const int n = n0 + ty*4 + i;
    #pragma unroll
    for (int j = 0; j < 4; j++){
      const int m = m0 + tx*4 + j;
      g[gbase + (size_t)n*FOURH + m] = acc[i][j] + bias[m];
    }
  }
}

// ---------------------------------------------------------------------------
// Sequential bidirectional scan — r7/r10 structure VERBATIM (best verified:
// 11.02ms profiled; gates in wave 0, serial sleep(1) poll, strided LDS
// partition, rcp gates, publish-first, __syncthreads barriers) with ONE
// change: the h-publish uses global_atomic_swap (no-return, sc1) instead of
// a plain store. Atomics must commit at the coherence point — they cannot
// dwell in store/write-combine buffers — so publish->visible latency drops
// to ~one hop. Wave 0's pre-poll vmcnt drain (~800cy of atomic acks) then
// covers most of the visibility window and the first sample should HIT.
// The out/h_n/c_n stores stay plain (no visibility requirement).
// ---------------------------------------------------------------------------
#define DPP_ROR_ADD(v, ctrl) do { \
    int _t = __builtin_amdgcn_update_dpp(0, __float_as_int(v), (ctrl), 0xf, 0xf, false); \
    (v) += __int_as_float(_t); } while (0)

__global__ __launch_bounds__(1024, 4) void scan_k(
    const float* __restrict__ Whh_f, const float* __restrict__ Whh_b,
    const float* __restrict__ c0, const float* __restrict__ g,
    float* __restrict__ hbuf, float* __restrict__ out)
{
  const int bx  = blockIdx.x;
  const int dir = bx >> 5;
  const int w   = bx & 31;
  const int j0  = w << 4;
  const int tid  = threadIdx.x;
  const int lane = tid & 63;
  const int wv   = tid >> 6;
  const int s    = lane & 31;         // k-slice id (32 slices x 16 strided cols)
  const int rb   = lane >> 5;
  const int r0   = (wv << 2) + rb;    // z-rows: wave wv covers rows 4wv..4wv+3
  const int r1   = r0 + 2;

  const float* __restrict__ Whh = dir ? Whh_b : Whh_f;

  __shared__ vf4  hsh4[128];          // h[t] broadcast, LINEAR chunks
  __shared__ float zbuf[64];
  __shared__ float gsh[64];
  __shared__ int dead;

  // Recurrent weights for rows r0/r1 over this lane's strided column set:
  // wX[4q+j] = W[row][128q + 4s + j]  (matches h4{a,b,c,d}[j] below).
  float wA[16], wB[16];
  {
    const int gA = r0 >> 4, hA = r0 & 15;
    const int gB = r1 >> 4, hB = r1 & 15;
    const float* pa = &Whh[(size_t)(gA*HH + j0 + hA)*HH];
    const float* pb = &Whh[(size_t)(gB*HH + j0 + hB)*HH];
    #pragma unroll
    for (int q = 0; q < 4; q++){
      float4 va = *(const float4*)&pa[q*128 + (s<<2)];
      wA[4*q+0]=va.x; wA[4*q+1]=va.y; wA[4*q+2]=va.z; wA[4*q+3]=va.w;
      float4 vb = *(const float4*)&pb[q*128 + (s<<2)];
      wB[4*q+0]=vb.x; wB[4*q+1]=vb.y; wB[4*q+2]=vb.z; wB[4*q+3]=vb.w;
    }
  }

  float cst = 0.f;
  if (tid < 16) cst = c0[dir*HH + j0 + tid];
  if (tid == 0) dead = 0;
  __syncthreads();

  float* __restrict__ hb = hbuf + (size_t)dir*(NSEQ+1)*HH;
  const float* __restrict__ gbp = g + (size_t)dir*NSEQ*FOURH;

  const bool gloader = (tid >= 64) && (tid < 80);
  const int  gl = tid - 64;

  for (int t = 0; t < NSEQ; t++){
    // g prefetch on wave 1 (off the polling wave's critical path).
    float pgi=0.f, pgf=0.f, pgg=0.f, pgo=0.f;
    if (gloader){
      const float* gp = &gbp[(size_t)t*FOURH + j0 + gl];
      pgi = gp[0]; pgf = gp[HH]; pgg = gp[2*HH]; pgo = gp[3*HH];
    }

    // Wave 0: poll h[t] (8 floats/lane) until no poison remains.
    // r7-proven serial form: issue+vmcnt(0)+check+sleep(1). The leading
    // vmcnt(0) also drains this wave's own publish-atomic acks — which
    // parks the poller through the visibility window for free.
    if (wv == 0){
      const float* hp = &hb[(size_t)t*HH + (lane<<3)];
      vf4 a, b;
      int it = 0;
      for (;;){
        ld2x16_dev(hp, a, b);
        bool ok = (__float_as_uint(a.x)!=POISON) & (__float_as_uint(a.y)!=POISON)
                & (__float_as_uint(a.z)!=POISON) & (__float_as_uint(a.w)!=POISON)
                & (__float_as_uint(b.x)!=POISON) & (__float_as_uint(b.y)!=POISON)
                & (__float_as_uint(b.z)!=POISON) & (__float_as_uint(b.w)!=POISON);
        if (ok) break;
        if (++it > POLL_CAP){ dead = 1; break; }
        __builtin_amdgcn_s_sleep(1);
      }
      // Linear LDS broadcast: lane L -> chunks {2L, 2L+1}.
      const int c0i = lane << 1;
      hsh4[c0i]     = a;
      hsh4[c0i + 1] = b;
    }
    __syncthreads();
    if (dead) break;

    // ---- read this lane's strided h slice: chunks {s, 32+s, 64+s, 96+s} ----
    vf4 h4a = hsh4[s];
    vf4 h4b = hsh4[32 + s];
    vf4 h4c = hsh4[64 + s];
    vf4 h4d = hsh4[96 + s];

    // Two 16-long dot products per lane (4 independent FMA chains).
    float a0=0.f, a1=0.f, b0=0.f, b1=0.f;
    a0 += wA[ 0]*h4a.x; a1 += wA[ 1]*h4a.y; a0 += wA[ 2]*h4a.z; a1 += wA[ 3]*h4a.w;
    a0 += wA[ 4]*h4b.x; a1 += wA[ 5]*h4b.y; a0 += wA[ 6]*h4b.z; a1 += wA[ 7]*h4b.w;
    a0 += wA[ 8]*h4c.x; a1 += wA[ 9]*h4c.y; a0 += wA[10]*h4c.z; a1 += wA[11]*h4c.w;
    a0 += wA[12]*h4d.x; a1 += wA[13]*h4d.y; a0 += wA[14]*h4d.z; a1 += wA[15]*h4d.w;
    b0 += wB[ 0]*h4a.x; b1 += wB[ 1]*h4a.y; b0 += wB[ 2]*h4a.z; b1 += wB[ 3]*h4a.w;
    b0 += wB[ 4]*h4b.x; b1 += wB[ 5]*h4b.y; b0 += wB[ 6]*h4b.z; b1 += wB[ 7]*h4b.w;
    b0 += wB[ 8]*h4c.x; b1 += wB[ 9]*h4c.y; b0 += wB[10]*h4c.z; b1 += wB[11]*h4c.w;
    b0 += wB[12]*h4d.x; b1 += wB[13]*h4d.y; b0 += wB[14]*h4d.z; b1 += wB[15]*h4d.w;
    float accA = a0 + a1, accB = b0 + b1;

    // Reduce across 32 k-slices: 4 DPP row-rotates (within 16) + xor-16 swizzle.
    DPP_ROR_ADD(accA, 0x128); DPP_ROR_ADD(accA, 0x124);
    DPP_ROR_ADD(accA, 0x122); DPP_ROR_ADD(accA, 0x121);
    accA += __int_as_float(__builtin_amdgcn_ds_swizzle(__float_as_int(accA), 0x401F));
    DPP_ROR_ADD(accB, 0x128); DPP_ROR_ADD(accB, 0x124);
    DPP_ROR_ADD(accB, 0x122); DPP_ROR_ADD(accB, 0x121);
    accB += __int_as_float(__builtin_amdgcn_ds_swizzle(__float_as_int(accB), 0x401F));

    if (s == 0){ zbuf[r0] = accA; zbuf[r1] = accB; }
    if (gloader){ gsh[gl]=pgi; gsh[16+gl]=pgf; gsh[32+gl]=pgg; gsh[48+gl]=pgo; }
    __syncthreads();

    // Gate math + state update for this wg's 16 hidden units.
    if (tid < 16){
      float zi = zbuf[tid]      + gsh[tid];
      float zf = zbuf[16 + tid] + gsh[16 + tid];
      float zg = zbuf[32 + tid] + gsh[32 + tid];
      float zo = zbuf[48 + tid] + gsh[48 + tid];
      float si = __builtin_amdgcn_rcpf(1.f + __expf(-zi));
      float sf = __builtin_amdgcn_rcpf(1.f + __expf(-zf));
      float so = __builtin_amdgcn_rcpf(1.f + __expf(-zo));
      float tg = 1.f - 2.f*__builtin_amdgcn_rcpf(__expf(2.f*zg) + 1.f);
      cst = sf*cst + si*tg;
      float tc = 1.f - 2.f*__builtin_amdgcn_rcpf(__expf(2.f*cst) + 1.f);
      float hv  = so*tc;
      uint32_t u = __float_as_uint(hv);
      if (u == POISON) hv = __uint_as_float(u ^ 1u);   // keep poison unambiguous

      st_pub(&hb[(size_t)(t+1)*HH + j0 + tid], hv);    // ATOMIC publish (coalesced line)

      const int n = dir ? (t ^ 7) : t;                 // undo per-sample reversal
      out[(size_t)n*(2*HH) + dir*HH + j0 + tid] = hv;

      if (t == NSEQ-1){
        out[(size_t)NSEQ*2*HH + dir*HH + j0 + tid] = hv;          // h_n
        out[(size_t)NSEQ*2*HH + 2*HH + dir*HH + j0 + tid] = cst;  // c_n
      }
    }
    // No trailing barrier: next-step hsh4/zbuf writes are gated behind the
    // barrier following wave 0's poll of h[t+1], which requires these gate
    // threads (in wave 0) to have finished publishing.
  }
}

// ---------------------------------------------------------------------------
extern "C" void kernel_launch(void* const* d_in, const int* in_sizes, int n_in,
                              void* d_out, int out_size, void* d_ws, size_t ws_size,
                              hipStream_t stream)
{
  const float* x    = (const float*)d_in[0];
  const float* h0   = (const float*)d_in[1];
  const float* c0   = (const float*)d_in[2];
  const float* Wihf = (const float*)d_in[3];
  const float* Whhf = (const float*)d_in[4];
  const float* bf   = (const float*)d_in[5];
  const float* Wihb = (const float*)d_in[6];
  const float* Whhb = (const float*)d_in[7];
  const float* bb   = (const float*)d_in[8];
  float* out = (float*)d_out;
  float* ws  = (float*)d_ws;

  float* g    = ws;                 // [2][8192][2048] fp32
  float* hbuf = ws + G_ELEMS;       // [2][8193][512]  fp32

  {
    int total = (int)HB_ELEMS;
    int blocks = (total + 255) / 256;
    init_hbuf_k<<<blocks, 256, 0, stream>>>(hbuf, h0);
  }
  {
    dim3 grid(NSEQ/64, (2*FOURH)/64);   // (128, 64)
    gemm_ih_k<<<grid, 256, 0, stream>>>(x, Wihf, bf, Wihb, bb, g);
  }
  scan_k<<<64, 1024, 0, stream>>>(Whhf, Whhb, c0, g, hbuf, out);
}